// Round 3
// baseline (109.945 us; speedup 1.0000x reference)
//
#include <hip/hip_runtime.h>
#include <hip/hip_cooperative_groups.h>
#include <hip/hip_bf16.h>
#include <math.h>

namespace cg = cooperative_groups;

#define HW 16384          // H*W
#define NCH 64            // C

// PWL table: per channel, o_j(x) sampled on uniform grid [-8,8), N=2048.
#define NG   2048
#define X0   (-8.0f)
#define INVDX 128.0f      // 1/DX
#define DX   0.0078125f   // 16/2048
#define PSTR (64*2048)    // plane stride (floats): [j][c][pt]

typedef __attribute__((ext_vector_type(8))) short s16x8;
typedef __attribute__((ext_vector_type(4))) short s16x4;
typedef __attribute__((ext_vector_type(2))) float f32x2;
typedef __attribute__((ext_vector_type(4))) float f32x4;
typedef __attribute__((ext_vector_type(8))) float f32x8;
typedef __attribute__((ext_vector_type(2))) __bf16 bf16x2;
typedef __attribute__((ext_vector_type(8))) __bf16 bf16x8;
typedef __attribute__((ext_vector_type(4))) unsigned u32x4;
typedef __attribute__((ext_vector_type(2))) unsigned u32x2;

__device__ __forceinline__ short bf16b(float f) {
    union { __hip_bfloat16 h; short s; } u;
    u.h = __float2bfloat16(f);
    return u.s;
}
__device__ __forceinline__ float bf2f(unsigned short us) {
    union { unsigned u; float f; } x;
    x.u = ((unsigned)us) << 16;
    return x.f;
}
__device__ __forceinline__ s16x8 cvt8(f32x8 v) {
    return __builtin_bit_cast(s16x8, __builtin_convertvector(v, bf16x8));
}
__device__ __forceinline__ unsigned pk_h1(f32x2 xw, f32x2 w, f32x2 b, f32x2 z2) {
    const f32x2 h = __builtin_elementwise_max(__builtin_elementwise_fma(xw, w, b), z2);
    return __builtin_bit_cast(unsigned, __builtin_convertvector(h, bf16x2));
}
__device__ __forceinline__ unsigned pk_relu_cvt(f32x2 v, f32x2 z2) {
    const f32x2 g = __builtin_elementwise_max(v, z2);
    return __builtin_bit_cast(unsigned, __builtin_convertvector(g, bf16x2));
}

#if __has_builtin(__builtin_amdgcn_mfma_f32_16x16x16bf16_1k)
#define HAVE_MFMA16 1
#else
#define HAVE_MFMA16 0
#endif

// One cooperative kernel, 256 blocks x 512 threads, 64KB LDS, 1 block/CU.
// Phase A (blocks 0..63): KAN PWL table build (c = blockIdx, 8 waves = 8 chunks)
// Phase B: gram (all blocks) + v_eval (remapped) — both read x directly
// Phase C: softmax+Wout fold + output GEMM
__global__ __launch_bounds__(512, 2) void fused_mhsa(
    const float* __restrict__ x,
    const float* __restrict__ W1, const float* __restrict__ b1,
    const float* __restrict__ W2, const float* __restrict__ b2,
    const float* __restrict__ W3, const float* __restrict__ b3,
    const float* __restrict__ temp, const float* __restrict__ Wout,
    const float* __restrict__ bout, float* __restrict__ out,
    float* __restrict__ table, float* __restrict__ dpart,
    unsigned short* __restrict__ vbuf)
{
    __shared__ __align__(16) unsigned char LB[65536];
    cg::grid_group grid = cg::this_grid();
    const int bi  = blockIdx.x;
    const int tid = threadIdx.x;

    // ================= Phase A: KAN table (blocks 0..63, c = bi) ==========
    if (bi < 64) {
        const int c = bi;
        float* W2s = (float*)LB;                   // 16KB
        float* W1s = (float*)(LB + 16384);
        float* B1s = (float*)(LB + 16640);
        float* B2s = (float*)(LB + 16896);
        {
            const float4* src = (const float4*)(W2 + c * 4096);
            float4* dst = (float4*)W2s;
            for (int i = tid; i < 1024; i += 512) dst[i] = src[i];
            if (tid < 64) {
                W1s[tid] = W1[c*64 + tid];
                B1s[tid] = b1[c*64 + tid];
                B2s[tid] = b2[c*64 + tid];
            }
        }
        __syncthreads();

        const int lane  = tid & 63;
        const int chunk = tid >> 6;              // wave id = chunk 0..7
        const int l15   = lane & 15;
        const int grp   = lane >> 4;
        const float* W3c = W3 + c * 192;

        s16x8 a1[4][2];
#pragma unroll
        for (int m = 0; m < 4; ++m)
#pragma unroll
            for (int s = 0; s < 2; ++s) {
                f32x8 w;
#pragma unroll
                for (int jj = 0; jj < 8; ++jj)
                    w[jj] = W2s[(s*32 + grp*8 + jj)*64 + m*16 + l15];
                a1[m][s] = cvt8(w);
            }

#if HAVE_MFMA16
        s16x4 a2[4];
#pragma unroll
        for (int m = 0; m < 4; ++m) {
            s16x4 f;
#pragma unroll
            for (int jj = 0; jj < 4; ++jj) {
                const int k = m*16 + grp*4 + jj;
                f[jj] = (l15 < 3) ? bf16b(W3c[k*3 + l15]) : (short)0;
            }
            a2[m] = f;
        }
        f32x4 b3r;
#pragma unroll
        for (int r = 0; r < 4; ++r) {
            const int row = grp*4 + r;
            b3r[r] = (row < 3) ? b3[c*3 + row] : 0.f;
        }
#else
        const float b3v0 = b3[c*3+0], b3v1 = b3[c*3+1], b3v2 = b3[c*3+2];
#endif

        float* Tq = table + c*NG;
        const char* b2base = (const char*)B2s;
        const f32x2 z2 = {0.f, 0.f};

        for (int t = 0; t < 16; ++t) {
            int z;
            asm volatile("v_mov_b32 %0, 0" : "=v"(z));

            const int pt = chunk*256 + t*16 + l15;
            const float xv = X0 + (float)pt * DX;
            const f32x2 xw = {xv, xv};

            s16x8 bf[2];
#pragma unroll
            for (int s = 0; s < 2; ++s) {
                const f32x4 w1lo = *(const f32x4*)&W1s[z + s*32 + grp*8];
                const f32x4 w1hi = *(const f32x4*)&W1s[z + s*32 + grp*8 + 4];
                const f32x4 b1lo = *(const f32x4*)&B1s[z + s*32 + grp*8];
                const f32x4 b1hi = *(const f32x4*)&B1s[z + s*32 + grp*8 + 4];
                u32x4 p;
                p[0] = pk_h1(xw, (f32x2){w1lo[0], w1lo[1]}, (f32x2){b1lo[0], b1lo[1]}, z2);
                p[1] = pk_h1(xw, (f32x2){w1lo[2], w1lo[3]}, (f32x2){b1lo[2], b1lo[3]}, z2);
                p[2] = pk_h1(xw, (f32x2){w1hi[0], w1hi[1]}, (f32x2){b1hi[0], b1hi[1]}, z2);
                p[3] = pk_h1(xw, (f32x2){w1hi[2], w1hi[3]}, (f32x2){b1hi[2], b1hi[3]}, z2);
                bf[s] = __builtin_bit_cast(s16x8, p);
            }

            f32x4 acc[4];
#pragma unroll
            for (int m = 0; m < 4; ++m) {
                acc[m] = *(const f32x4*)(b2base + (m*64 + grp*16 + z));
                acc[m] = __builtin_amdgcn_mfma_f32_16x16x32_bf16(a1[m][0], bf[0], acc[m], 0, 0, 0);
                acc[m] = __builtin_amdgcn_mfma_f32_16x16x32_bf16(a1[m][1], bf[1], acc[m], 0, 0, 0);
            }

#if HAVE_MFMA16
            s16x4 bb[4];
#pragma unroll
            for (int m = 0; m < 4; ++m) {
                u32x2 pv;
                pv[0] = pk_relu_cvt((f32x2){acc[m][0], acc[m][1]}, z2);
                pv[1] = pk_relu_cvt((f32x2){acc[m][2], acc[m][3]}, z2);
                bb[m] = __builtin_bit_cast(s16x4, pv);
            }
            f32x4 acc2a = b3r;
            f32x4 acc2b = {0.f, 0.f, 0.f, 0.f};
            acc2a = __builtin_amdgcn_mfma_f32_16x16x16bf16_1k(a2[0], bb[0], acc2a, 0, 0, 0);
            acc2b = __builtin_amdgcn_mfma_f32_16x16x16bf16_1k(a2[1], bb[1], acc2b, 0, 0, 0);
            acc2a = __builtin_amdgcn_mfma_f32_16x16x16bf16_1k(a2[2], bb[2], acc2a, 0, 0, 0);
            acc2b = __builtin_amdgcn_mfma_f32_16x16x16bf16_1k(a2[3], bb[3], acc2b, 0, 0, 0);
            if (grp == 0) {
                Tq[pt]          = acc2a[0] + acc2b[0];
                Tq[PSTR + pt]   = acc2a[1] + acc2b[1];
                Tq[2*PSTR + pt] = acc2a[2] + acc2b[2];
            }
#else
            float po0 = 0.f, po1 = 0.f, po2 = 0.f;
#pragma unroll
            for (int m = 0; m < 4; ++m)
#pragma unroll
                for (int r = 0; r < 4; ++r) {
                    const float g = fmaxf(acc[m][r], 0.f);
                    const int k = m*16 + grp*4 + r;
                    po0 = fmaf(g, W3c[k*3+0], po0);
                    po1 = fmaf(g, W3c[k*3+1], po1);
                    po2 = fmaf(g, W3c[k*3+2], po2);
                }
            po0 += __shfl_xor(po0, 16, 64); po0 += __shfl_xor(po0, 32, 64);
            po1 += __shfl_xor(po1, 16, 64); po1 += __shfl_xor(po1, 32, 64);
            po2 += __shfl_xor(po2, 16, 64); po2 += __shfl_xor(po2, 32, 64);
            if (grp == 0) {
                Tq[pt]          = po0 + b3v0;
                Tq[PSTR + pt]   = po1 + b3v1;
                Tq[2*PSTR + pt] = po2 + b3v2;
            }
#endif
        }
    }

    grid.sync();   // table visible to all blocks

    // ================= Phase B1: gram (all 256 blocks) ====================
    {
        const int bhd = bi >> 4;                 // b*8+hd
        const int spl = bi & 15;
        const int b = bhd >> 3, hd = bhd & 7;
        const int w   = tid >> 6;
        const int l   = tid & 63;
        const int grp = l >> 4;
        const int i16 = l & 15;
        const int ch  = i16 & 7;
        const int usek = i16 >> 3;

        unsigned short* T = (unsigned short*)LB;  // [2][8][NG] = 64KB

        __syncthreads();                          // phase A LDS reads done
        for (int e = tid; e < 8192; e += 512) {
            const int map = e >> 12;
            const int rem = e & 4095;
            const int c8  = rem >> 9;
            const int g   = rem & 511;
            const int gm  = map*64 + hd*8 + c8;
            const int cc  = gm / 3;
            const int jj  = gm % 3;
            const float4 v = ((const float4*)(table + jj*PSTR + cc*NG))[g];
            u32x2 pk;
            pk[0] = ((unsigned)(unsigned short)bf16b(v.x)) | (((unsigned)(unsigned short)bf16b(v.y)) << 16);
            pk[1] = ((unsigned)(unsigned short)bf16b(v.z)) | (((unsigned)(unsigned short)bf16b(v.w)) << 16);
            *(u32x2*)&T[(map*8 + c8)*NG + g*4] = pk;
        }
        __syncthreads();

        const unsigned short* Tc = &T[(usek*8 + ch)*NG];
        const int gm = usek*64 + hd*8 + ch;
        const int cx = gm / 3;
        const float* xp = x + (b*NCH + cx)*HW + spl*1024 + grp*8;

        f32x4 gacc = {0.f, 0.f, 0.f, 0.f};
#pragma unroll
        for (int s = 0; s < 4; ++s) {
            const int slab = w*4 + s;
            const float* xs = xp + slab*32;
            const f32x4 xlo = *(const f32x4*)xs;
            const f32x4 xhi = *(const f32x4*)(xs + 4);
            f32x8 vals;
#pragma unroll
            for (int e = 0; e < 8; ++e) {
                const float xv = (e < 4) ? xlo[e] : xhi[e-4];
                const float u = (xv - X0) * INVDX;
                int idx = (int)u;
                idx = min(max(idx, 0), NG - 2);
                const float fr = u - (float)idx;
                const float t0 = bf2f(Tc[idx]);
                const float t1 = bf2f(Tc[idx+1]);
                vals[e] = fmaf(fr, t1 - t0, t0);
            }
            const s16x8 frag = cvt8(vals);
            gacc = __builtin_amdgcn_mfma_f32_16x16x32_bf16(frag, frag, gacc, 0, 0, 0);
        }

        __syncthreads();
        float* red = (float*)LB;                 // 8 waves x 256 floats
#pragma unroll
        for (int r = 0; r < 4; ++r)
            red[w*256 + (grp*4 + r)*16 + i16] = gacc[r];
        __syncthreads();

        if (tid < 256) {
            const int row = tid >> 4, col = tid & 15;
            float g = 0.f;
#pragma unroll
            for (int ww = 0; ww < 8; ++ww) g += red[ww*256 + tid];
            int p = -1;
            if (row < 8 && col >= 8)        p = row*8 + (col - 8);
            else if (row == col && row < 8) p = 64 + row;
            else if (row == col)            p = 72 + (row - 8);
            if (p >= 0) dpart[(bhd*16 + spl)*80 + p] = g;
        }
        __syncthreads();                          // red reads done
    }

    // ================= Phase B2: v_eval (remapped onto 256 blocks) ========
    {
        const int m    = bi >> 2;                // v-channel 0..63
        const int half = bi & 3;                 // 4 x 8192 px
        const int gm   = 128 + m;
        const int cx   = gm / 3;
        const int jj   = gm % 3;

        float* Lv = (float*)LB;                  // 8KB
        ((float4*)Lv)[tid] = ((const float4*)(table + jj*PSTR + cx*NG))[tid];
        __syncthreads();

        const int pbase = half * 8192;           // 8192 | 16384 -> no b cross
        const int b  = pbase >> 14;
        const int hw = pbase & 16383;
        const float* xr = x + (b*NCH + cx)*HW + hw;
        unsigned short* vr = vbuf + (b*NCH + m)*HW + hw;

        for (int i = 0; i < 8; ++i) {
            const int off = i*1024 + tid*2;
            const float2 xv = *(const float2*)(xr + off);
            float o[2];
#pragma unroll
            for (int e = 0; e < 2; ++e) {
                const float u = ((e ? xv.y : xv.x) - X0) * INVDX;
                int idx = (int)u;
                idx = min(max(idx, 0), NG - 2);
                const float fr = u - (float)idx;
                const float v0 = Lv[idx], v1 = Lv[idx+1];
                o[e] = fmaf(fr, v1 - v0, v0);
            }
            ushort2 vs;
            vs.x = (unsigned short)bf16b(o[0]);
            vs.y = (unsigned short)bf16b(o[1]);
            *(ushort2*)(vr + off) = vs;
        }
    }

    grid.sync();   // dpart + vbuf visible to all blocks

    // ================= Phase C: attn fold + output GEMM ===================
    {
        const int b   = bi >> 7;                 // 2
        const int qtr = (bi >> 5) & 3;           // 4 quarters of 16 outs
        const int tp  = bi & 31;                 // 32 tile-pairs of 512 px
        const int n   = tp*512 + tid;

        float*  D     = (float*)LB;              // [8][80]
        float*  attnS = (float*)(LB + 2560);     // [8][8][8]
        float4* AtS   = (float4*)(LB + 4608);    // [64][4]

        for (int idx = tid; idx < 640; idx += 512) {
            const int g = idx / 80, p = idx % 80;
            float s = 0.f;
            for (int spl = 0; spl < 16; ++spl)
                s += dpart[((b*8 + g)*16 + spl)*80 + p];
            D[g*80 + p] = s;
        }
        __syncthreads();

        if (tid < 64) {
            const int hd = tid >> 3, i = tid & 7;
            const float invq = 1.f / fmaxf(sqrtf(D[hd*80 + 64 + i]), 1e-12f);
            const float T = temp[hd];
            float l[8];
            float m = -1e30f;
#pragma unroll
            for (int j = 0; j < 8; ++j) {
                const float invk = 1.f / fmaxf(sqrtf(D[hd*80 + 72 + j]), 1e-12f);
                l[j] = D[hd*80 + i*8 + j] * invq * invk * T;
                m = fmaxf(m, l[j]);
            }
            float s = 0.f;
#pragma unroll
            for (int j = 0; j < 8; ++j) { l[j] = expf(l[j] - m); s += l[j]; }
            const float inv = 1.f / s;
#pragma unroll
            for (int j = 0; j < 8; ++j) attnS[(hd*8 + i)*8 + j] = l[j] * inv;
        }
        __syncthreads();

        if (tid < 256) {
            const int cv = tid & 63, oq = tid >> 6;
            const int hd = cv >> 3, jj = cv & 7;
            float res[4];
#pragma unroll
            for (int oo = 0; oo < 4; ++oo) {
                const int o = qtr*16 + oq*4 + oo;
                float s = 0.f;
#pragma unroll
                for (int i = 0; i < 8; ++i)
                    s = fmaf(Wout[o*64 + hd*8 + i], attnS[(hd*8 + i)*8 + jj], s);
                res[oo] = s;
            }
            AtS[cv*4 + oq] = make_float4(res[0], res[1], res[2], res[3]);
        }
        __syncthreads();

        float acc[16];
#pragma unroll
        for (int o = 0; o < 16; ++o) acc[o] = 0.f;

        const unsigned short* vbase = vbuf + (b*NCH)*HW + n;
        for (int cv = 0; cv < 64; ++cv) {
            const float vv = bf2f(vbase[cv*HW]);
#pragma unroll
            for (int o4 = 0; o4 < 4; ++o4) {
                const float4 w = AtS[cv*4 + o4];
                acc[4*o4+0] = fmaf(w.x, vv, acc[4*o4+0]);
                acc[4*o4+1] = fmaf(w.y, vv, acc[4*o4+1]);
                acc[4*o4+2] = fmaf(w.z, vv, acc[4*o4+2]);
                acc[4*o4+3] = fmaf(w.w, vv, acc[4*o4+3]);
            }
        }
#pragma unroll
        for (int o = 0; o < 16; ++o) {
            const int oc = qtr*16 + o;
            out[(b*NCH + oc)*HW + n] = acc[o] + bout[oc];
        }
    }
}

// ---------------- launcher ----------------
extern "C" void kernel_launch(void* const* d_in, const int* in_sizes, int n_in,
                              void* d_out, int out_size, void* d_ws, size_t ws_size,
                              hipStream_t stream) {
    const float* x    = (const float*)d_in[0];
    const float* W1   = (const float*)d_in[1];
    const float* b1   = (const float*)d_in[2];
    const float* W2   = (const float*)d_in[3];
    const float* b2   = (const float*)d_in[4];
    const float* W3   = (const float*)d_in[5];
    const float* b3   = (const float*)d_in[6];
    const float* temp = (const float*)d_in[7];
    const float* Wout = (const float*)d_in[8];
    const float* bout = (const float*)d_in[9];
    float* out = (float*)d_out;

    float* ws = (float*)d_ws;
    float* table = ws;                               // 3*64*2048 = 393216 f32
    float* dpart = ws + 393216;                      // 256*80 = 20480 f32
    unsigned short* vbuf = (unsigned short*)(ws + 393216 + 20480); // 2*64*16384 bf16

    void* args[] = {
        (void*)&x, (void*)&W1, (void*)&b1, (void*)&W2, (void*)&b2,
        (void*)&W3, (void*)&b3, (void*)&temp, (void*)&Wout, (void*)&bout,
        (void*)&out, (void*)&table, (void*)&dpart, (void*)&vbuf
    };
    hipLaunchCooperativeKernel((const void*)fused_mhsa, dim3(256), dim3(512),
                               args, 0, stream);
}

// Round 5
// 51.978 us; speedup vs baseline: 2.1152x; 2.1152x over previous
//
#include <hip/hip_runtime.h>
#include <hip/hip_bf16.h>
#include <math.h>

#define HW 16384          // H*W
#define NCH 64            // C

// PWL table: per channel, o_j(x) sampled on uniform grid [-8,8), N=2048.
#define NG   2048
#define X0   (-8.0f)
#define INVDX 128.0f      // 1/DX
#define DX   0.0078125f   // 16/2048
#define PSTR (64*2048)    // plane stride (floats): [j][c][pt]

typedef __attribute__((ext_vector_type(8))) short s16x8;
typedef __attribute__((ext_vector_type(4))) short s16x4;
typedef __attribute__((ext_vector_type(2))) float f32x2;
typedef __attribute__((ext_vector_type(4))) float f32x4;
typedef __attribute__((ext_vector_type(8))) float f32x8;
typedef __attribute__((ext_vector_type(2))) __bf16 bf16x2;
typedef __attribute__((ext_vector_type(8))) __bf16 bf16x8;
typedef __attribute__((ext_vector_type(4))) unsigned u32x4;
typedef __attribute__((ext_vector_type(2))) unsigned u32x2;

__device__ __forceinline__ short bf16b(float f) {
    union { __hip_bfloat16 h; short s; } u;
    u.h = __float2bfloat16(f);
    return u.s;
}
__device__ __forceinline__ float bf2f(unsigned short us) {
    union { unsigned u; float f; } x;
    x.u = ((unsigned)us) << 16;
    return x.f;
}
__device__ __forceinline__ s16x8 cvt8(f32x8 v) {
    return __builtin_bit_cast(s16x8, __builtin_convertvector(v, bf16x8));
}
__device__ __forceinline__ unsigned pk_h1(f32x2 xw, f32x2 w, f32x2 b, f32x2 z2) {
    const f32x2 h = __builtin_elementwise_max(__builtin_elementwise_fma(xw, w, b), z2);
    return __builtin_bit_cast(unsigned, __builtin_convertvector(h, bf16x2));
}
__device__ __forceinline__ unsigned pk_relu_cvt(f32x2 v, f32x2 z2) {
    const f32x2 g = __builtin_elementwise_max(v, z2);
    return __builtin_bit_cast(unsigned, __builtin_convertvector(g, bf16x2));
}

#if __has_builtin(__builtin_amdgcn_mfma_f32_16x16x16bf16_1k)
#define HAVE_MFMA16 1
#else
#define HAVE_MFMA16 0
#endif

// ---------------- Phase 0: tabulate per-channel KAN maps on the grid ------
// R4: 1024 blocks (64 ch x 16 chunks of 128 pts, 8 iters) -> 4 waves/CU.
__global__ __launch_bounds__(64, 4) void kan_grid_mfma(
    const float* __restrict__ W1,   // [64][64]
    const float* __restrict__ b1,   // [64][64]
    const float* __restrict__ W2,   // [64][64][64]
    const float* __restrict__ b2,   // [64][64]
    const float* __restrict__ W3,   // [64][64][3]
    const float* __restrict__ b3,   // [64][3]
    float* __restrict__ table)      // [3][64][2048]
{
    const int c     = blockIdx.x & 63;
    const int chunk = blockIdx.x >> 6;       // 0..15, 128 grid pts each
    const int lane  = threadIdx.x;           // 0..63
    const int l15   = lane & 15;
    const int grp   = lane >> 4;

    __shared__ float W2s[4096];              // 16KB: W2c staged coalesced
    __shared__ float W1s[64], B1s[64], B2s[64];
    {
        const float4* src = (const float4*)(W2 + c * 4096);
        float4* dst = (float4*)W2s;
        for (int i = lane; i < 1024; i += 64) dst[i] = src[i];
        W1s[lane] = W1[c*64 + lane];
        B1s[lane] = b1[c*64 + lane];
        B2s[lane] = b2[c*64 + lane];
    }
    __syncthreads();

    const float* W3c = W3 + c * 192;

    // A1 = W2T frags from LDS (broadcast reads)
    s16x8 a1[4][2];
#pragma unroll
    for (int m = 0; m < 4; ++m)
#pragma unroll
        for (int s = 0; s < 2; ++s) {
            f32x8 w;
#pragma unroll
            for (int jj = 0; jj < 8; ++jj)
                w[jj] = W2s[(s*32 + grp*8 + jj)*64 + m*16 + l15];
            a1[m][s] = cvt8(w);
        }

#if HAVE_MFMA16
    s16x4 a2[4];
#pragma unroll
    for (int m = 0; m < 4; ++m) {
        s16x4 f;
#pragma unroll
        for (int jj = 0; jj < 4; ++jj) {
            const int k = m*16 + grp*4 + jj;
            f[jj] = (l15 < 3) ? bf16b(W3c[k*3 + l15]) : (short)0;
        }
        a2[m] = f;
    }
    f32x4 b3r;
#pragma unroll
    for (int r = 0; r < 4; ++r) {
        const int row = grp*4 + r;
        b3r[r] = (row < 3) ? b3[c*3 + row] : 0.f;
    }
#else
    const float b3v0 = b3[c*3+0], b3v1 = b3[c*3+1], b3v2 = b3[c*3+2];
#endif

    float* Tq = table + c*NG;
    const char* b2base = (const char*)B2s;
    const f32x2 z2 = {0.f, 0.f};

    for (int t = 0; t < 8; ++t) {
        int z;
        asm volatile("v_mov_b32 %0, 0" : "=v"(z));

        const int pt = chunk*128 + t*16 + l15;
        const float xv = X0 + (float)pt * DX;
        const f32x2 xw = {xv, xv};

        s16x8 bf[2];
#pragma unroll
        for (int s = 0; s < 2; ++s) {
            const f32x4 w1lo = *(const f32x4*)&W1s[z + s*32 + grp*8];
            const f32x4 w1hi = *(const f32x4*)&W1s[z + s*32 + grp*8 + 4];
            const f32x4 b1lo = *(const f32x4*)&B1s[z + s*32 + grp*8];
            const f32x4 b1hi = *(const f32x4*)&B1s[z + s*32 + grp*8 + 4];
            u32x4 p;
            p[0] = pk_h1(xw, (f32x2){w1lo[0], w1lo[1]}, (f32x2){b1lo[0], b1lo[1]}, z2);
            p[1] = pk_h1(xw, (f32x2){w1lo[2], w1lo[3]}, (f32x2){b1lo[2], b1lo[3]}, z2);
            p[2] = pk_h1(xw, (f32x2){w1hi[0], w1hi[1]}, (f32x2){b1hi[0], b1hi[1]}, z2);
            p[3] = pk_h1(xw, (f32x2){w1hi[2], w1hi[3]}, (f32x2){b1hi[2], b1hi[3]}, z2);
            bf[s] = __builtin_bit_cast(s16x8, p);
        }

        f32x4 acc[4];
#pragma unroll
        for (int m = 0; m < 4; ++m) {
            acc[m] = *(const f32x4*)(b2base + (m*64 + grp*16 + z));
            acc[m] = __builtin_amdgcn_mfma_f32_16x16x32_bf16(a1[m][0], bf[0], acc[m], 0, 0, 0);
            acc[m] = __builtin_amdgcn_mfma_f32_16x16x32_bf16(a1[m][1], bf[1], acc[m], 0, 0, 0);
        }

#if HAVE_MFMA16
        s16x4 bb[4];
#pragma unroll
        for (int m = 0; m < 4; ++m) {
            u32x2 pv;
            pv[0] = pk_relu_cvt((f32x2){acc[m][0], acc[m][1]}, z2);
            pv[1] = pk_relu_cvt((f32x2){acc[m][2], acc[m][3]}, z2);
            bb[m] = __builtin_bit_cast(s16x4, pv);
        }
        f32x4 acc2a = b3r;
        f32x4 acc2b = {0.f, 0.f, 0.f, 0.f};
        acc2a = __builtin_amdgcn_mfma_f32_16x16x16bf16_1k(a2[0], bb[0], acc2a, 0, 0, 0);
        acc2b = __builtin_amdgcn_mfma_f32_16x16x16bf16_1k(a2[1], bb[1], acc2b, 0, 0, 0);
        acc2a = __builtin_amdgcn_mfma_f32_16x16x16bf16_1k(a2[2], bb[2], acc2a, 0, 0, 0);
        acc2b = __builtin_amdgcn_mfma_f32_16x16x16bf16_1k(a2[3], bb[3], acc2b, 0, 0, 0);
        if (grp == 0) {
            Tq[pt]          = acc2a[0] + acc2b[0];
            Tq[PSTR + pt]   = acc2a[1] + acc2b[1];
            Tq[2*PSTR + pt] = acc2a[2] + acc2b[2];
        }
#else
        float po0 = 0.f, po1 = 0.f, po2 = 0.f;
#pragma unroll
        for (int m = 0; m < 4; ++m)
#pragma unroll
            for (int r = 0; r < 4; ++r) {
                const float g = fmaxf(acc[m][r], 0.f);
                const int k = m*16 + grp*4 + r;
                po0 = fmaf(g, W3c[k*3+0], po0);
                po1 = fmaf(g, W3c[k*3+1], po1);
                po2 = fmaf(g, W3c[k*3+2], po2);
            }
        po0 += __shfl_xor(po0, 16, 64); po0 += __shfl_xor(po0, 32, 64);
        po1 += __shfl_xor(po1, 16, 64); po1 += __shfl_xor(po1, 32, 64);
        po2 += __shfl_xor(po2, 16, 64); po2 += __shfl_xor(po2, 32, 64);
        if (grp == 0) {
            Tq[pt]          = po0 + b3v0;
            Tq[PSTR + pt]   = po1 + b3v1;
            Tq[2*PSTR + pt] = po2 + b3v2;
        }
#endif
    }
}

// ---------------- Phase 1a: head-major Gram via MFMA (q,k never hit HBM) --
// R4: 512 blocks (16 bhd x 32 splits of 512 px) -> 2 blocks/CU = 16 waves/CU.
// Gram partials accumulated with float atomics into D[16][80].
__global__ __launch_bounds__(512) void gram_kernel(
    const float* __restrict__ x, const float* __restrict__ table,
    float* __restrict__ Dglob)
{
    const int bhd = blockIdx.x >> 5;         // 0..15 (b*8+hd)
    const int spl = blockIdx.x & 31;         // 32 splits x 512 px
    const int b = bhd >> 3, hd = bhd & 7;
    const int tid = threadIdx.x;             // 0..511
    const int w   = tid >> 6;                // wave 0..7
    const int l   = tid & 63;
    const int grp = l >> 4;                  // k-group 0..3
    const int i16 = l & 15;                  // Gram row/col 0..15
    const int ch  = i16 & 7;                 // channel within head
    const int usek = i16 >> 3;               // 0 = q row, 1 = k row

    __shared__ unsigned short T[2][8][NG];   // 64KB bf16 tables (q,k x 8ch)

    for (int e = tid; e < 8192; e += 512) {
        const int map = e >> 12;             // 0=q slot, 1=k slot
        const int rem = e & 4095;
        const int c8  = rem >> 9;            // 512 float4 per channel slot
        const int g   = rem & 511;
        const int gm  = map*64 + hd*8 + c8;  // global qkv channel
        const int cc  = gm / 3;              // KAN channel
        const int jj  = gm % 3;              // table plane
        const float4 v = ((const float4*)(table + jj*PSTR + cc*NG))[g];
        u32x2 pk;
        pk[0] = ((unsigned)(unsigned short)bf16b(v.x)) | (((unsigned)(unsigned short)bf16b(v.y)) << 16);
        pk[1] = ((unsigned)(unsigned short)bf16b(v.z)) | (((unsigned)(unsigned short)bf16b(v.w)) << 16);
        *(u32x2*)&T[map][c8][g*4] = pk;
    }
    __syncthreads();

    const unsigned short* Tc = T[usek][ch];
    const int gm = usek*64 + hd*8 + ch;      // this row's global channel
    const int cx = gm / 3;                   // input x channel
    const float* xp = x + (b*NCH + cx)*HW + spl*512 + grp*8;

    f32x4 gacc = {0.f, 0.f, 0.f, 0.f};
#pragma unroll
    for (int s = 0; s < 2; ++s) {
        const int slab = w*2 + s;            // 0..15 (16 slabs of 32 px)
        const float* xs = xp + slab*32;
        const f32x4 xlo = *(const f32x4*)xs;
        const f32x4 xhi = *(const f32x4*)(xs + 4);
        f32x8 vals;
#pragma unroll
        for (int e = 0; e < 8; ++e) {
            const float xv = (e < 4) ? xlo[e] : xhi[e-4];
            const float u = (xv - X0) * INVDX;
            int idx = (int)u;
            idx = min(max(idx, 0), NG - 2);
            const float fr = u - (float)idx;
            const float t0 = bf2f(Tc[idx]);
            const float t1 = bf2f(Tc[idx+1]);
            vals[e] = fmaf(fr, t1 - t0, t0);
        }
        const s16x8 frag = cvt8(vals);
        gacc = __builtin_amdgcn_mfma_f32_16x16x32_bf16(frag, frag, gacc, 0, 0, 0);
    }

    // cross-wave reduce of the 16x16 Gram (tables dead -> reuse LDS)
    __syncthreads();
    float* red = (float*)&T[0][0][0];        // 8 waves x 256 floats = 8KB
#pragma unroll
    for (int r = 0; r < 4; ++r)
        red[w*256 + (grp*4 + r)*16 + i16] = gacc[r];
    __syncthreads();

    if (tid < 256) {
        const int row = tid >> 4, col = tid & 15;
        float g = 0.f;
#pragma unroll
        for (int ww = 0; ww < 8; ++ww) g += red[ww*256 + tid];
        int p = -1;
        if (row < 8 && col >= 8)        p = row*8 + (col - 8);   // q_i . k_j
        else if (row == col && row < 8) p = 64 + row;            // q_i . q_i
        else if (row == col)            p = 72 + (row - 8);      // k_j . k_j
        if (p >= 0) atomicAdd(&Dglob[bhd*80 + p], g);
    }
}

// ---------------- Phase 1b: evaluate v only, store bf16 -------------------
// R4: 1024 blocks (64 ch x 16 chunks of 2048 px) -> 16 waves/CU.
__global__ __launch_bounds__(256) void v_eval(
    const float* __restrict__ x, const float* __restrict__ table,
    unsigned short* __restrict__ vbuf)
{
    const int m     = blockIdx.x >> 4;       // v-channel 0..63
    const int chunk = blockIdx.x & 15;       // 16 chunks x 2048 px
    const int t     = threadIdx.x;
    const int gm    = 128 + m;               // global qkv channel
    const int cx    = gm / 3;                // KAN / x channel
    const int jj    = gm % 3;                // table plane

    __shared__ float Lv[NG];
    const float4* Tv = (const float4*)(table + jj*PSTR + cx*NG);
    for (int i = t; i < NG/4; i += 256) ((float4*)Lv)[i] = Tv[i];
    __syncthreads();

    const int pxbase = chunk * 2048;         // never crosses batch
    const int b  = pxbase >> 14;
    const int hw = pxbase & 16383;
    const float* xr = x + (b*NCH + cx)*HW + hw;
    unsigned short* vr = vbuf + (b*NCH + m)*HW + hw;

    for (int i = 0; i < 4; ++i) {
        const int off = i*512 + t*2;
        const float2 xv = *(const float2*)(xr + off);
        float o[2];
#pragma unroll
        for (int e = 0; e < 2; ++e) {
            const float u = ((e ? xv.y : xv.x) - X0) * INVDX;
            int idx = (int)u;
            idx = min(max(idx, 0), NG - 2);
            const float fr = u - (float)idx;
            const float v0 = Lv[idx], v1 = Lv[idx+1];
            o[e] = fmaf(fr, v1 - v0, v0);
        }
        ushort2 vs;
        vs.x = (unsigned short)bf16b(o[0]);
        vs.y = (unsigned short)bf16b(o[1]);
        *(ushort2*)(vr + off) = vs;
    }
}

// ---------------- Phase 3: fused attn (softmax+Wout fold) + output GEMM ----
// R4: 1024 blocks (2b x 8 out-groups x 64 tiles of 256 px) -> 16 waves/CU;
// D comes pre-reduced from gram's atomics. R5 fix: AtS[64][4] (was [64][2],
// OOB writes/reads at oq=1 -> corruption).
__global__ __launch_bounds__(256) void out_kernel(
    const unsigned short* __restrict__ vbuf, const float* __restrict__ Dglob,
    const float* __restrict__ temp, const float* __restrict__ Wout,
    const float* __restrict__ bout, float* __restrict__ out)
{
    const int b    = blockIdx.x >> 9;          // 2
    const int og   = (blockIdx.x >> 6) & 7;    // 8 groups of 8 outs
    const int tile = blockIdx.x & 63;          // 64 tiles of 256 px
    const int n = tile * 256 + threadIdx.x;
    const int t = threadIdx.x;                 // 0..255

    __shared__ float D[8][80];
    __shared__ float attnS[8][8][8];
    __shared__ float2 AtS[64][4];              // At[cv][og*8 .. +8) as 4 float2

    for (int idx = t; idx < 640; idx += 256)
        ((float*)D)[idx] = Dglob[b*640 + idx];
    __syncthreads();

    if (t < 64) {
        const int hd = t >> 3, i = t & 7;
        const float invq = 1.f / fmaxf(sqrtf(D[hd][64+i]), 1e-12f);
        const float T = temp[hd];
        float l[8];
        float m = -1e30f;
#pragma unroll
        for (int j = 0; j < 8; ++j) {
            const float invk = 1.f / fmaxf(sqrtf(D[hd][72+j]), 1e-12f);
            l[j] = D[hd][i*8+j] * invq * invk * T;
            m = fmaxf(m, l[j]);
        }
        float s = 0.f;
#pragma unroll
        for (int j = 0; j < 8; ++j) { l[j] = expf(l[j] - m); s += l[j]; }
        const float inv = 1.f / s;
#pragma unroll
        for (int j = 0; j < 8; ++j) attnS[hd][i][j] = l[j] * inv;
    }
    __syncthreads();

    if (t < 128) {
        const int cv = t & 63, oq = t >> 6;       // oq in {0,1}
        const int hd = cv >> 3, jj = cv & 7;
        float res[4];
#pragma unroll
        for (int oo = 0; oo < 4; ++oo) {
            const int o = og*8 + oq*4 + oo;
            float s = 0.f;
#pragma unroll
            for (int i = 0; i < 8; ++i)
                s = fmaf(Wout[o*64 + hd*8 + i], attnS[hd][i][jj], s);
            res[oo] = s;
        }
        AtS[cv][oq*2 + 0] = make_float2(res[0], res[1]);
        AtS[cv][oq*2 + 1] = make_float2(res[2], res[3]);
    }
    __syncthreads();

    float acc[8];
#pragma unroll
    for (int o = 0; o < 8; ++o) acc[o] = 0.f;

    const unsigned short* vbase = vbuf + (b*NCH)*HW + n;
    for (int cv = 0; cv < 64; ++cv) {
        const float vv = bf2f(vbase[cv*HW]);
        const float2 w0 = AtS[cv][0];
        const float2 w1 = AtS[cv][1];
        const float2 w2 = AtS[cv][2];
        const float2 w3 = AtS[cv][3];
        acc[0] = fmaf(w0.x, vv, acc[0]);
        acc[1] = fmaf(w0.y, vv, acc[1]);
        acc[2] = fmaf(w1.x, vv, acc[2]);
        acc[3] = fmaf(w1.y, vv, acc[3]);
        acc[4] = fmaf(w2.x, vv, acc[4]);
        acc[5] = fmaf(w2.y, vv, acc[5]);
        acc[6] = fmaf(w3.x, vv, acc[6]);
        acc[7] = fmaf(w3.y, vv, acc[7]);
    }
#pragma unroll
    for (int o = 0; o < 8; ++o) {
        const int oc = og*8 + o;
        out[(b*NCH + oc)*HW + n] = acc[o] + bout[oc];
    }
}

// ---------------- launcher ----------------
extern "C" void kernel_launch(void* const* d_in, const int* in_sizes, int n_in,
                              void* d_out, int out_size, void* d_ws, size_t ws_size,
                              hipStream_t stream) {
    const float* x    = (const float*)d_in[0];
    const float* W1   = (const float*)d_in[1];
    const float* b1   = (const float*)d_in[2];
    const float* W2   = (const float*)d_in[3];
    const float* b2   = (const float*)d_in[4];
    const float* W3   = (const float*)d_in[5];
    const float* b3   = (const float*)d_in[6];
    const float* temp = (const float*)d_in[7];
    const float* Wout = (const float*)d_in[8];
    const float* bout = (const float*)d_in[9];
    float* out = (float*)d_out;

    float* ws = (float*)d_ws;
    float* table = ws;                               // 3*64*2048 = 393216 f32
    float* Dglob = ws + 393216;                      // 16*80 = 1280 f32
    unsigned short* vbuf = (unsigned short*)(ws + 393216 + 1280); // 2*64*16384 bf16

    hipMemsetAsync(Dglob, 0, 1280 * sizeof(float), stream);
    kan_grid_mfma<<<1024, 64, 0, stream>>>(W1, b1, W2, b2, W3, b3, table);
    gram_kernel<<<512, 512, 0, stream>>>(x, table, Dglob);
    v_eval<<<1024, 256, 0, stream>>>(x, table, vbuf);
    out_kernel<<<1024, 256, 0, stream>>>(vbuf, Dglob, temp, Wout, bout, out);
}

// Round 6
// 43.885 us; speedup vs baseline: 2.5053x; 1.1844x over previous
//
#include <hip/hip_runtime.h>
#include <hip/hip_bf16.h>
#include <math.h>

#define HW 16384          // H*W
#define NCH 64            // C

// PWL table: per channel, o_j(x) sampled on uniform grid [-8,8), N=2048.
#define NG   2048
#define X0   (-8.0f)
#define INVDX 128.0f      // 1/DX
#define DX   0.0078125f   // 16/2048
#define PSTR (64*2048)    // plane stride (floats/ushorts): [j][c][pt]

typedef __attribute__((ext_vector_type(8))) short s16x8;
typedef __attribute__((ext_vector_type(4))) short s16x4;
typedef __attribute__((ext_vector_type(2))) float f32x2;
typedef __attribute__((ext_vector_type(4))) float f32x4;
typedef __attribute__((ext_vector_type(8))) float f32x8;
typedef __attribute__((ext_vector_type(2))) __bf16 bf16x2;
typedef __attribute__((ext_vector_type(8))) __bf16 bf16x8;
typedef __attribute__((ext_vector_type(4))) unsigned u32x4;
typedef __attribute__((ext_vector_type(2))) unsigned u32x2;

__device__ __forceinline__ short bf16b(float f) {
    union { __hip_bfloat16 h; short s; } u;
    u.h = __float2bfloat16(f);
    return u.s;
}
__device__ __forceinline__ float bf2f(unsigned short us) {
    union { unsigned u; float f; } x;
    x.u = ((unsigned)us) << 16;
    return x.f;
}
__device__ __forceinline__ s16x8 cvt8(f32x8 v) {
    return __builtin_bit_cast(s16x8, __builtin_convertvector(v, bf16x8));
}
__device__ __forceinline__ unsigned pk_h1(f32x2 xw, f32x2 w, f32x2 b, f32x2 z2) {
    const f32x2 h = __builtin_elementwise_max(__builtin_elementwise_fma(xw, w, b), z2);
    return __builtin_bit_cast(unsigned, __builtin_convertvector(h, bf16x2));
}
__device__ __forceinline__ unsigned pk_relu_cvt(f32x2 v, f32x2 z2) {
    const f32x2 g = __builtin_elementwise_max(v, z2);
    return __builtin_bit_cast(unsigned, __builtin_convertvector(g, bf16x2));
}

#if __has_builtin(__builtin_amdgcn_mfma_f32_16x16x16bf16_1k)
#define HAVE_MFMA16 1
#else
#define HAVE_MFMA16 0
#endif

// ---------------- Phase 0: tabulate per-channel KAN maps on the grid ------
// 1024 blocks (64 ch x 16 chunks of 128 pts). Writes f32 table (for v_eval)
// AND bf16 mirror (for gram staging). Block 0 zeroes Dglob (visible to the
// next kernel at the dispatch boundary).
__global__ __launch_bounds__(64, 4) void kan_grid_mfma(
    const float* __restrict__ W1,   // [64][64]
    const float* __restrict__ b1,   // [64][64]
    const float* __restrict__ W2,   // [64][64][64]
    const float* __restrict__ b2,   // [64][64]
    const float* __restrict__ W3,   // [64][64][3]
    const float* __restrict__ b3,   // [64][3]
    float* __restrict__ table,      // [3][64][2048] f32
    unsigned short* __restrict__ tableBF,  // [3][64][2048] bf16
    float* __restrict__ Dglob)      // [16][80]
{
    const int c     = blockIdx.x & 63;
    const int chunk = blockIdx.x >> 6;       // 0..15, 128 grid pts each
    const int lane  = threadIdx.x;           // 0..63
    const int l15   = lane & 15;
    const int grp   = lane >> 4;

    if (blockIdx.x == 0) {
        for (int i = lane; i < 1280; i += 64) Dglob[i] = 0.f;
    }

    __shared__ float W2s[4096];              // 16KB: W2c staged coalesced
    __shared__ float W1s[64], B1s[64], B2s[64];
    {
        const float4* src = (const float4*)(W2 + c * 4096);
        float4* dst = (float4*)W2s;
        for (int i = lane; i < 1024; i += 64) dst[i] = src[i];
        W1s[lane] = W1[c*64 + lane];
        B1s[lane] = b1[c*64 + lane];
        B2s[lane] = b2[c*64 + lane];
    }
    __syncthreads();

    const float* W3c = W3 + c * 192;

    // A1 = W2T frags from LDS (broadcast reads)
    s16x8 a1[4][2];
#pragma unroll
    for (int m = 0; m < 4; ++m)
#pragma unroll
        for (int s = 0; s < 2; ++s) {
            f32x8 w;
#pragma unroll
            for (int jj = 0; jj < 8; ++jj)
                w[jj] = W2s[(s*32 + grp*8 + jj)*64 + m*16 + l15];
            a1[m][s] = cvt8(w);
        }

#if HAVE_MFMA16
    s16x4 a2[4];
#pragma unroll
    for (int m = 0; m < 4; ++m) {
        s16x4 f;
#pragma unroll
        for (int jj = 0; jj < 4; ++jj) {
            const int k = m*16 + grp*4 + jj;
            f[jj] = (l15 < 3) ? bf16b(W3c[k*3 + l15]) : (short)0;
        }
        a2[m] = f;
    }
    f32x4 b3r;
#pragma unroll
    for (int r = 0; r < 4; ++r) {
        const int row = grp*4 + r;
        b3r[r] = (row < 3) ? b3[c*3 + row] : 0.f;
    }
#else
    const float b3v0 = b3[c*3+0], b3v1 = b3[c*3+1], b3v2 = b3[c*3+2];
#endif

    float* Tq = table + c*NG;
    unsigned short* TqB = tableBF + c*NG;
    const char* b2base = (const char*)B2s;
    const f32x2 z2 = {0.f, 0.f};

    for (int t = 0; t < 8; ++t) {
        int z;
        asm volatile("v_mov_b32 %0, 0" : "=v"(z));

        const int pt = chunk*128 + t*16 + l15;
        const float xv = X0 + (float)pt * DX;
        const f32x2 xw = {xv, xv};

        s16x8 bf[2];
#pragma unroll
        for (int s = 0; s < 2; ++s) {
            const f32x4 w1lo = *(const f32x4*)&W1s[z + s*32 + grp*8];
            const f32x4 w1hi = *(const f32x4*)&W1s[z + s*32 + grp*8 + 4];
            const f32x4 b1lo = *(const f32x4*)&B1s[z + s*32 + grp*8];
            const f32x4 b1hi = *(const f32x4*)&B1s[z + s*32 + grp*8 + 4];
            u32x4 p;
            p[0] = pk_h1(xw, (f32x2){w1lo[0], w1lo[1]}, (f32x2){b1lo[0], b1lo[1]}, z2);
            p[1] = pk_h1(xw, (f32x2){w1lo[2], w1lo[3]}, (f32x2){b1lo[2], b1lo[3]}, z2);
            p[2] = pk_h1(xw, (f32x2){w1hi[0], w1hi[1]}, (f32x2){b1hi[0], b1hi[1]}, z2);
            p[3] = pk_h1(xw, (f32x2){w1hi[2], w1hi[3]}, (f32x2){b1hi[2], b1hi[3]}, z2);
            bf[s] = __builtin_bit_cast(s16x8, p);
        }

        f32x4 acc[4];
#pragma unroll
        for (int m = 0; m < 4; ++m) {
            acc[m] = *(const f32x4*)(b2base + (m*64 + grp*16 + z));
            acc[m] = __builtin_amdgcn_mfma_f32_16x16x32_bf16(a1[m][0], bf[0], acc[m], 0, 0, 0);
            acc[m] = __builtin_amdgcn_mfma_f32_16x16x32_bf16(a1[m][1], bf[1], acc[m], 0, 0, 0);
        }

#if HAVE_MFMA16
        s16x4 bb[4];
#pragma unroll
        for (int m = 0; m < 4; ++m) {
            u32x2 pv;
            pv[0] = pk_relu_cvt((f32x2){acc[m][0], acc[m][1]}, z2);
            pv[1] = pk_relu_cvt((f32x2){acc[m][2], acc[m][3]}, z2);
            bb[m] = __builtin_bit_cast(s16x4, pv);
        }
        f32x4 acc2a = b3r;
        f32x4 acc2b = {0.f, 0.f, 0.f, 0.f};
        acc2a = __builtin_amdgcn_mfma_f32_16x16x16bf16_1k(a2[0], bb[0], acc2a, 0, 0, 0);
        acc2b = __builtin_amdgcn_mfma_f32_16x16x16bf16_1k(a2[1], bb[1], acc2b, 0, 0, 0);
        acc2a = __builtin_amdgcn_mfma_f32_16x16x16bf16_1k(a2[2], bb[2], acc2a, 0, 0, 0);
        acc2b = __builtin_amdgcn_mfma_f32_16x16x16bf16_1k(a2[3], bb[3], acc2b, 0, 0, 0);
        if (grp == 0) {
            const float o0 = acc2a[0] + acc2b[0];
            const float o1 = acc2a[1] + acc2b[1];
            const float o2 = acc2a[2] + acc2b[2];
            Tq[pt]          = o0;
            Tq[PSTR + pt]   = o1;
            Tq[2*PSTR + pt] = o2;
            TqB[pt]          = (unsigned short)bf16b(o0);
            TqB[PSTR + pt]   = (unsigned short)bf16b(o1);
            TqB[2*PSTR + pt] = (unsigned short)bf16b(o2);
        }
#else
        float po0 = 0.f, po1 = 0.f, po2 = 0.f;
#pragma unroll
        for (int m = 0; m < 4; ++m)
#pragma unroll
            for (int r = 0; r < 4; ++r) {
                const float g = fmaxf(acc[m][r], 0.f);
                const int k = m*16 + grp*4 + r;
                po0 = fmaf(g, W3c[k*3+0], po0);
                po1 = fmaf(g, W3c[k*3+1], po1);
                po2 = fmaf(g, W3c[k*3+2], po2);
            }
        po0 += __shfl_xor(po0, 16, 64); po0 += __shfl_xor(po0, 32, 64);
        po1 += __shfl_xor(po1, 16, 64); po1 += __shfl_xor(po1, 32, 64);
        po2 += __shfl_xor(po2, 16, 64); po2 += __shfl_xor(po2, 32, 64);
        if (grp == 0) {
            const float o0 = po0 + b3v0, o1 = po1 + b3v1, o2 = po2 + b3v2;
            Tq[pt]          = o0;
            Tq[PSTR + pt]   = o1;
            Tq[2*PSTR + pt] = o2;
            TqB[pt]          = (unsigned short)bf16b(o0);
            TqB[PSTR + pt]   = (unsigned short)bf16b(o1);
            TqB[2*PSTR + pt] = (unsigned short)bf16b(o2);
        }
#endif
    }
}

// ---------------- Phase 1: gram (blocks 0..511) || v_eval (512..1023) ----
// gram: 16 bhd x 32 splits of 512 px; Gram 16x16 via MFMA, atomics into
// Dglob[16][80]. v: 64 ch x 8 chunks of 4096 px, bf16 store.
__global__ __launch_bounds__(512) void gram_v(
    const float* __restrict__ x, const float* __restrict__ table,
    const unsigned short* __restrict__ tableBF,
    float* __restrict__ Dglob, unsigned short* __restrict__ vbuf)
{
    __shared__ __align__(16) unsigned char LB[65536];
    const int bi  = blockIdx.x;
    const int tid = threadIdx.x;             // 0..511

    if (bi < 512) {
        // ---------------- gram ----------------
        const int bhd = bi >> 5;             // 0..15 (b*8+hd)
        const int spl = bi & 31;             // 32 splits x 512 px
        const int b = bhd >> 3, hd = bhd & 7;
        const int w   = tid >> 6;            // wave 0..7
        const int l   = tid & 63;
        const int grp = l >> 4;              // px-group 0..3
        const int i16 = l & 15;              // Gram row/col 0..15
        const int ch  = i16 & 7;             // channel within head
        const int usek = i16 >> 3;           // 0 = q row, 1 = k row

        unsigned short* T = (unsigned short*)LB;  // [2][8][NG] = 64KB

        // stage bf16 tables: 4096 x ushort8 copies (no cvt)
        for (int e = tid; e < 4096; e += 512) {
            const int map = e >> 11;
            const int rem = e & 2047;
            const int c8  = rem >> 8;        // 256 ushort8 per channel
            const int g   = rem & 255;
            const int gm  = map*64 + hd*8 + c8;
            const int cc  = gm / 3;
            const int jj  = gm % 3;
            const u32x4 v = ((const u32x4*)(tableBF + jj*PSTR + cc*NG))[g];
            *(u32x4*)&T[(map*8 + c8)*NG + g*8] = v;
        }
        __syncthreads();

        const unsigned short* Tc = &T[(usek*8 + ch)*NG];
        const int gm = usek*64 + hd*8 + ch;
        const int cx = gm / 3;
        const float* xp = x + (b*NCH + cx)*HW + spl*512 + grp*8;

        f32x4 gacc = {0.f, 0.f, 0.f, 0.f};
#pragma unroll
        for (int s = 0; s < 2; ++s) {
            const int slab = w*2 + s;        // 0..15 (16 slabs of 32 px)
            const float* xs = xp + slab*32;
            const f32x4 xlo = *(const f32x4*)xs;
            const f32x4 xhi = *(const f32x4*)(xs + 4);
            f32x8 vals;
#pragma unroll
            for (int e = 0; e < 8; ++e) {
                const float xv = (e < 4) ? xlo[e] : xhi[e-4];
                const float u = (xv - X0) * INVDX;
                int idx = (int)u;
                idx = min(max(idx, 0), NG - 2);
                const float fr = u - (float)idx;
                const float t0 = bf2f(Tc[idx]);
                const float t1 = bf2f(Tc[idx+1]);
                vals[e] = fmaf(fr, t1 - t0, t0);
            }
            const s16x8 frag = cvt8(vals);
            gacc = __builtin_amdgcn_mfma_f32_16x16x32_bf16(frag, frag, gacc, 0, 0, 0);
        }

        // cross-wave reduce (tables dead -> reuse LDS)
        __syncthreads();
        float* red = (float*)LB;             // 8 waves x 256 floats
#pragma unroll
        for (int r = 0; r < 4; ++r)
            red[w*256 + (grp*4 + r)*16 + i16] = gacc[r];
        __syncthreads();

        if (tid < 256) {
            const int row = tid >> 4, col = tid & 15;
            float g = 0.f;
#pragma unroll
            for (int ww = 0; ww < 8; ++ww) g += red[ww*256 + tid];
            int p = -1;
            if (row < 8 && col >= 8)        p = row*8 + (col - 8);
            else if (row == col && row < 8) p = 64 + row;
            else if (row == col)            p = 72 + (row - 8);
            if (p >= 0) atomicAdd(&Dglob[bhd*80 + p], g);
        }
    } else {
        // ---------------- v_eval ----------------
        const int bi2   = bi - 512;
        const int m     = bi2 >> 3;          // v-channel 0..63
        const int chunk = bi2 & 7;           // 8 chunks x 4096 px
        const int gm    = 128 + m;
        const int cx    = gm / 3;
        const int jj    = gm % 3;

        float* Lv = (float*)LB;              // 8KB
        ((float4*)Lv)[tid] = ((const float4*)(table + jj*PSTR + cx*NG))[tid];
        __syncthreads();

        const int pxbase = chunk * 4096;     // 4 chunks/batch, never crosses
        const int b  = pxbase >> 14;
        const int hw = pxbase & 16383;
        const float* xr = x + (b*NCH + cx)*HW + hw;
        unsigned short* vr = vbuf + (b*NCH + m)*HW + hw;

        for (int i = 0; i < 4; ++i) {
            const int off = i*1024 + tid*2;
            const float2 xv = *(const float2*)(xr + off);
            float o[2];
#pragma unroll
            for (int e = 0; e < 2; ++e) {
                const float u = ((e ? xv.y : xv.x) - X0) * INVDX;
                int idx = (int)u;
                idx = min(max(idx, 0), NG - 2);
                const float fr = u - (float)idx;
                const float v0 = Lv[idx], v1 = Lv[idx+1];
                o[e] = fmaf(fr, v1 - v0, v0);
            }
            ushort2 vs;
            vs.x = (unsigned short)bf16b(o[0]);
            vs.y = (unsigned short)bf16b(o[1]);
            *(ushort2*)(vr + off) = vs;
        }
    }
}

// ---------------- Phase 2: fused attn (softmax+Wout fold) + output GEMM ----
// 1024 blocks (2b x 8 out-groups x 64 tiles of 256 px) -> 16 waves/CU.
__global__ __launch_bounds__(256) void out_kernel(
    const unsigned short* __restrict__ vbuf, const float* __restrict__ Dglob,
    const float* __restrict__ temp, const float* __restrict__ Wout,
    const float* __restrict__ bout, float* __restrict__ out)
{
    const int b    = blockIdx.x >> 9;          // 2
    const int og   = (blockIdx.x >> 6) & 7;    // 8 groups of 8 outs
    const int tile = blockIdx.x & 63;          // 64 tiles of 256 px
    const int n = tile * 256 + threadIdx.x;
    const int t = threadIdx.x;                 // 0..255

    __shared__ float D[8][80];
    __shared__ float attnS[8][8][8];
    __shared__ float2 AtS[64][4];              // At[cv][og*8 .. +8) as 4 float2

    for (int idx = t; idx < 640; idx += 256)
        ((float*)D)[idx] = Dglob[b*640 + idx];
    __syncthreads();

    if (t < 64) {
        const int hd = t >> 3, i = t & 7;
        const float invq = 1.f / fmaxf(sqrtf(D[hd][64+i]), 1e-12f);
        const float T = temp[hd];
        float l[8];
        float m = -1e30f;
#pragma unroll
        for (int j = 0; j < 8; ++j) {
            const float invk = 1.f / fmaxf(sqrtf(D[hd][72+j]), 1e-12f);
            l[j] = D[hd][i*8+j] * invq * invk * T;
            m = fmaxf(m, l[j]);
        }
        float s = 0.f;
#pragma unroll
        for (int j = 0; j < 8; ++j) { l[j] = expf(l[j] - m); s += l[j]; }
        const float inv = 1.f / s;
#pragma unroll
        for (int j = 0; j < 8; ++j) attnS[hd][i][j] = l[j] * inv;
    }
    __syncthreads();

    if (t < 128) {
        const int cv = t & 63, oq = t >> 6;       // oq in {0,1}
        const int hd = cv >> 3, jj = cv & 7;
        float res[4];
#pragma unroll
        for (int oo = 0; oo < 4; ++oo) {
            const int o = og*8 + oq*4 + oo;
            float s = 0.f;
#pragma unroll
            for (int i = 0; i < 8; ++i)
                s = fmaf(Wout[o*64 + hd*8 + i], attnS[hd][i][jj], s);
            res[oo] = s;
        }
        AtS[cv][oq*2 + 0] = make_float2(res[0], res[1]);
        AtS[cv][oq*2 + 1] = make_float2(res[2], res[3]);
    }
    __syncthreads();

    float acc[8];
#pragma unroll
    for (int o = 0; o < 8; ++o) acc[o] = 0.f;

    const unsigned short* vbase = vbuf + (b*NCH)*HW + n;
    for (int cv = 0; cv < 64; ++cv) {
        const float vv = bf2f(vbase[cv*HW]);
        const float2 w0 = AtS[cv][0];
        const float2 w1 = AtS[cv][1];
        const float2 w2 = AtS[cv][2];
        const float2 w3 = AtS[cv][3];
        acc[0] = fmaf(w0.x, vv, acc[0]);
        acc[1] = fmaf(w0.y, vv, acc[1]);
        acc[2] = fmaf(w1.x, vv, acc[2]);
        acc[3] = fmaf(w1.y, vv, acc[3]);
        acc[4] = fmaf(w2.x, vv, acc[4]);
        acc[5] = fmaf(w2.y, vv, acc[5]);
        acc[6] = fmaf(w3.x, vv, acc[6]);
        acc[7] = fmaf(w3.y, vv, acc[7]);
    }
#pragma unroll
    for (int o = 0; o < 8; ++o) {
        const int oc = og*8 + o;
        out[(b*NCH + oc)*HW + n] = acc[o] + bout[oc];
    }
}

// ---------------- launcher ----------------
extern "C" void kernel_launch(void* const* d_in, const int* in_sizes, int n_in,
                              void* d_out, int out_size, void* d_ws, size_t ws_size,
                              hipStream_t stream) {
    const float* x    = (const float*)d_in[0];
    const float* W1   = (const float*)d_in[1];
    const float* b1   = (const float*)d_in[2];
    const float* W2   = (const float*)d_in[3];
    const float* b2   = (const float*)d_in[4];
    const float* W3   = (const float*)d_in[5];
    const float* b3   = (const float*)d_in[6];
    const float* temp = (const float*)d_in[7];
    const float* Wout = (const float*)d_in[8];
    const float* bout = (const float*)d_in[9];
    float* out = (float*)d_out;

    float* ws = (float*)d_ws;
    float* table = ws;                                   // 393216 f32
    unsigned short* tableBF = (unsigned short*)(ws + 393216);  // 393216 bf16 = 196608 f32 words
    float* Dglob = ws + 393216 + 196608;                 // 1280 f32
    unsigned short* vbuf = (unsigned short*)(ws + 393216 + 196608 + 1280);

    kan_grid_mfma<<<1024, 64, 0, stream>>>(W1, b1, W2, b2, W3, b3, table, tableBF, Dglob);
    gram_v<<<1024, 512, 0, stream>>>(x, table, tableBF, Dglob, vbuf);
    out_kernel<<<1024, 256, 0, stream>>>(vbuf, Dglob, temp, Wout, bout, out);
}